// Round 7
// baseline (285.103 us; speedup 1.0000x reference)
//
#include <hip/hip_runtime.h>

typedef unsigned short u16;
typedef unsigned int u32;
typedef __bf16 bf16x8 __attribute__((ext_vector_type(8)));
typedef float f32x4 __attribute__((ext_vector_type(4)));
typedef short s16x4 __attribute__((ext_vector_type(4)));

#define AS1 __attribute__((address_space(1)))
#define AS3 __attribute__((address_space(3)))

__device__ __forceinline__ f32x4 mfma16(bf16x8 a, bf16x8 b, f32x4 c) {
    return __builtin_amdgcn_mfma_f32_16x16x32_bf16(a, b, c, 0, 0, 0);
}
// K=16 shape: B-operand layout == C/D layout (transpose-free PV)
__device__ __forceinline__ f32x4 mfma16k16(s16x4 a, s16x4 b, f32x4 c) {
    return __builtin_amdgcn_mfma_f32_16x16x16bf16_1k(a, b, c, 0, 0, 0);
}

__device__ __forceinline__ u16 f2bf(float f) {
    return __builtin_bit_cast(u16, (__bf16)f);
}

__device__ __forceinline__ void gld16(const u16* g, u16* l) {
    __builtin_amdgcn_global_load_lds((AS1 void*)g, (AS3 void*)l, 16, 0, 0);
}

// ---------------- fused fp32 -> bf16 conversion ----------------
__global__ __launch_bounds__(256) void cvt_all(const float* __restrict__ q, const float* __restrict__ k,
                                               const float* __restrict__ v, const float* __restrict__ wq,
                                               const float* __restrict__ wk, const float* __restrict__ wv,
                                               const float* __restrict__ wo, u16* __restrict__ qo,
                                               u16* __restrict__ ko, u16* __restrict__ vo,
                                               u16* __restrict__ wqo, u16* __restrict__ wko,
                                               u16* __restrict__ wvo, u16* __restrict__ woo) {
    const int y = blockIdx.y;
    const float* x; u16* o; int n;
    switch (y) {
        case 0: x = q; o = qo; n = 4 << 20; break;
        case 1: x = k; o = ko; n = 4 << 20; break;
        case 2: x = v; o = vo; n = 4 << 20; break;
        case 3: x = wq; o = wqo; n = 1 << 20; break;
        case 4: x = wk; o = wko; n = 1 << 20; break;
        case 5: x = wv; o = wvo; n = 1 << 20; break;
        default: x = wo; o = woo; n = 1 << 20; break;
    }
    int i = (blockIdx.x * 256 + threadIdx.x) * 4;
    if (i >= n) return;
    float4 vv = *(const float4*)(x + i);
    u32 lo = (u32)f2bf(vv.x) | ((u32)f2bf(vv.y) << 16);
    u32 hi = (u32)f2bf(vv.z) | ((u32)f2bf(vv.w) << 16);
    *(uint2*)(o + i) = make_uint2(lo, hi);
}

// ---------------- GEMM: C[.,N] = A[.,K] @ Bt[N,K]^T (frozen this round) ----------------
template <int BM, int BN, bool BF16OUT>
__device__ __forceinline__ void gemm_core(const u16* __restrict__ A, const u16* __restrict__ Bt,
                                          void* __restrict__ Cp, int K, int N, int m0, int n0,
                                          float oscale) {
    constexpr int WROWS = BM / 64;
    constexpr int WCOLS = 4 / WROWS;
    constexpr int BFR = BN / WCOLS / 16;
    __shared__ __align__(16) u16 As[BM * 32];
    __shared__ __align__(16) u16 Bs[BN * 32];
    const int tid = threadIdx.x;
    const int lane = tid & 63, wave = tid >> 6;
    const int l16 = lane & 15, q4 = lane >> 4;
    const int wm = (wave / WCOLS) * 64, wn = (wave % WCOLS) * (BFR * 16);

    const f32x4 fz = {0.f, 0.f, 0.f, 0.f};
    f32x4 acc[4][BFR];
#pragma unroll
    for (int i = 0; i < 4; ++i)
#pragma unroll
        for (int j = 0; j < BFR; ++j) acc[i][j] = fz;

    const int rseg = lane >> 2;
    const int ck = ((lane & 3) ^ ((lane >> 3) & 3)) * 8;
    const u16* Ag = A + (size_t)(m0 + wave * 16 + rseg) * K + ck;
    const u16* Bg = Bt + (size_t)(n0 + wave * 16 + rseg) * K + ck;

    const int swz = (q4 ^ ((l16 & 7) >> 1)) * 8;

    for (int k0 = 0; k0 < K; k0 += 32) {
        __syncthreads();
#pragma unroll
        for (int p = 0; p < BM / 64; ++p)
            gld16(Ag + (size_t)p * 64 * K + k0, As + p * 2048 + wave * 512);
#pragma unroll
        for (int p = 0; p < BN / 64; ++p)
            gld16(Bg + (size_t)p * 64 * K + k0, Bs + p * 2048 + wave * 512);
        __syncthreads();
        bf16x8 af[4], bfr[BFR];
#pragma unroll
        for (int i = 0; i < 4; ++i)
            af[i] = *(const bf16x8*)&As[(wm + i * 16 + l16) * 32 + swz];
#pragma unroll
        for (int j = 0; j < BFR; ++j)
            bfr[j] = *(const bf16x8*)&Bs[(wn + j * 16 + l16) * 32 + swz];
#pragma unroll
        for (int i = 0; i < 4; ++i)
#pragma unroll
            for (int j = 0; j < BFR; ++j) acc[i][j] = mfma16(af[i], bfr[j], acc[i][j]);
    }

#pragma unroll
    for (int i = 0; i < 4; ++i) {
        const int row = m0 + wm + i * 16 + q4 * 4;
#pragma unroll
        for (int j = 0; j < BFR; ++j) {
            const int col = n0 + wn + j * 16 + l16;
#pragma unroll
            for (int r = 0; r < 4; ++r) {
                const float vr = acc[i][j][r] * oscale;
                if constexpr (BF16OUT)
                    ((u16*)Cp)[(size_t)(row + r) * N + col] = f2bf(vr);
                else
                    ((float*)Cp)[(size_t)(row + r) * N + col] = vr;
            }
        }
    }
}

// z=0: Q = query@wq^T (pre-scaled by 0.125*log2e); z=1: K = key@wk^T;
// z=2: Vt = wv @ value^T -> VtAll[h*64+dv][b*2048+s]
__global__ __launch_bounds__(256) void gemm_qkv(const u16* __restrict__ qb, const u16* __restrict__ kb,
                                                const u16* __restrict__ vb, const u16* __restrict__ wqb,
                                                const u16* __restrict__ wkb, const u16* __restrict__ wvb,
                                                u16* __restrict__ Qp, u16* __restrict__ Kp,
                                                u16* __restrict__ VtAll) {
    const int z = blockIdx.y, x = blockIdx.x;
    const u16 *A, *Bt;
    u16* C;
    int N, m0, n0;
    float sc = 1.0f;
    if (z == 0) {
        A = qb; Bt = wqb; C = Qp; N = 1024; m0 = (x >> 3) * 128; n0 = (x & 7) * 128;
        sc = 0.18033688011112042f;  // (1/sqrt(64)) * log2(e)
    } else if (z == 1) {
        A = kb; Bt = wkb; C = Kp; N = 1024; m0 = (x >> 3) * 128; n0 = (x & 7) * 128;
    } else {
        A = wvb; Bt = vb; C = VtAll; N = 4096; m0 = (x >> 5) * 128; n0 = (x & 31) * 128;
    }
    gemm_core<128, 128, true>(A, Bt, C, 1024, N, m0, n0, sc);
}

__global__ __launch_bounds__(256) void gemm_out(const u16* __restrict__ ctx,
                                                const u16* __restrict__ wob,
                                                float* __restrict__ out) {
    const int x = blockIdx.x;
    gemm_core<64, 128, false>(ctx, wob, out, 1024, 1024, (x >> 3) * 64, (x & 7) * 128, 1.0f);
}

// ---------------- Flash attention: K async-dbuf in LDS, V direct from global ------------
// Loop t: barrier (vmcnt(0) drain = readiness of buf[t]) -> issue gld16 for t+1 into
// buf[t^1] (safe: t-1's readers of buf[t^1] are past the barrier; drained at barrier t+1)
// -> compute t. True async prefetch: gld16 overlaps a full tile of compute.
// Ks rows unpadded (64 elems), 8-chunk XOR swizzle c^(row&7): staging is gld16-contiguous
// (lane*16B), fragment reads 2-way bank aliasing (free). V^T A-frags (8 B/lane) read
// straight from global: per (dt,nt) instr = 16 rows x 32 B; 4 nt cover one 128 B line/row.
__global__ __launch_bounds__(256) void flash_attn(const u16* __restrict__ Qp,
                                                  const u16* __restrict__ Kp,
                                                  const u16* __restrict__ VtAll,
                                                  u16* __restrict__ Ctx) {
    constexpr int D = 1024, SS = 2048;
    __shared__ __align__(16) u16 Ks[2][64 * 64];  // [buf][s_row][dk], chunk-swizzled

    const int tid = threadIdx.x;
    const int lane = tid & 63, wave = tid >> 6;
    const int l16 = lane & 15, q4 = lane >> 4;
    const int h = blockIdx.y, b = blockIdx.z;
    const int q0 = blockIdx.x * 128 + wave * 32;

    bf16x8 qf[2][2];
#pragma unroll
    for (int qs = 0; qs < 2; ++qs) {
        const u16* Qb = Qp + (size_t)(b * SS + q0 + qs * 16 + l16) * D + h * 64;
        qf[qs][0] = *(const bf16x8*)(Qb + q4 * 8);
        qf[qs][1] = *(const bf16x8*)(Qb + 32 + q4 * 8);
    }

    const f32x4 fz = {0.f, 0.f, 0.f, 0.f};
    f32x4 ot[2][4], lacc[2];
    lacc[0] = fz; lacc[1] = fz;
#pragma unroll
    for (int qs = 0; qs < 2; ++qs)
#pragma unroll
        for (int dt = 0; dt < 4; ++dt) ot[qs][dt] = fz;

    s16x4 onesA;
    onesA[0] = onesA[1] = onesA[2] = onesA[3] = (short)0x3F80;  // bf16 1.0

    // K staging: thread covers rows sr and sr+32; global source chunk XOR'd so that
    // chunk c of row r lands at position c^(r&7); LDS dest = wave-uniform + lane*16.
    const int sr = tid >> 3;
    const int ck = ((lane & 7) ^ (lane >> 3)) * 8;
    const u16* Kg = Kp + (size_t)(b * SS + sr) * D + h * 64 + ck;
    const int ldsW = wave * 512;  // u16 elements; = wave*1024 B

    // V: per-lane base (row l16, col chunk q4*4); add dt*16 rows and kt+nt*16 cols
    const u16* Vlane = VtAll + (size_t)(h * 64 + l16) * 4096 + (size_t)b * SS + q4 * 4;

    // preload tile 0 into buf 0
    gld16(Kg, (u16*)Ks[0] + ldsW);
    gld16(Kg + (size_t)32 * D, (u16*)Ks[0] + ldsW + 2048);

    const int pos = (q4 ^ (l16 & 7)) * 8;  // K-frag chunk position (dk-low); dk-high = pos^32

    for (int kt = 0; kt < SS; kt += 64) {
        const int buf = (kt >> 6) & 1;
        __syncthreads();  // vmcnt(0)+barrier: Ks[buf] ready, buf^1 free to overwrite
        if (kt + 64 < SS) {  // async prefetch next K tile; lands by next barrier
            const u16* Kn = Kg + (size_t)(kt + 64) * D;
            gld16(Kn, (u16*)Ks[buf ^ 1] + ldsW);
            gld16(Kn + (size_t)32 * D, (u16*)Ks[buf ^ 1] + ldsW + 2048);
        }

        // V fragments for this tile (global; latency hidden under QK+exp2)
        s16x4 vf[4][4];
#pragma unroll
        for (int dt = 0; dt < 4; ++dt)
#pragma unroll
            for (int nt = 0; nt < 4; ++nt)
                vf[dt][nt] = *(const s16x4*)(Vlane + (size_t)dt * 16 * 4096 + kt + nt * 16);

        // S^T = K·Q^T (exp2 domain; Q pre-scaled by 0.125*log2e)
        f32x4 st[2][4];
#pragma unroll
        for (int nt = 0; nt < 4; ++nt) {
            const int R = (nt * 16 + l16) * 64;
            const bf16x8 ka = *(const bf16x8*)&Ks[buf][R + pos];
            const bf16x8 kbf = *(const bf16x8*)&Ks[buf][R + (pos ^ 32)];
#pragma unroll
            for (int qs = 0; qs < 2; ++qs) {
                f32x4 s = mfma16(ka, qf[qs][0], fz);
                st[qs][nt] = mfma16(kbf, qf[qs][1], s);
            }
        }
        // P^T = exp2(S^T), in-register (K=16 B-frag layout)
        s16x4 p[2][4];
#pragma unroll
        for (int qs = 0; qs < 2; ++qs)
#pragma unroll
            for (int nt = 0; nt < 4; ++nt) {
                s16x4 pk;
#pragma unroll
                for (int r = 0; r < 4; ++r)
                    pk[r] = (short)f2bf(__builtin_amdgcn_exp2f(st[qs][nt][r]));
                p[qs][nt] = pk;
            }
        // O^T += V^T·P^T ; l via ones-MFMA (every reg = l[q=l16])
#pragma unroll
        for (int nt = 0; nt < 4; ++nt) {
#pragma unroll
            for (int dt = 0; dt < 4; ++dt) {
                ot[0][dt] = mfma16k16(vf[dt][nt], p[0][nt], ot[0][dt]);
                ot[1][dt] = mfma16k16(vf[dt][nt], p[1][nt], ot[1][dt]);
            }
            lacc[0] = mfma16k16(onesA, p[0][nt], lacc[0]);
            lacc[1] = mfma16k16(onesA, p[1][nt], lacc[1]);
        }
    }

    // normalize + direct bf16 ctx write (lacc broadcast: all regs hold l[q=l16])
#pragma unroll
    for (int qs = 0; qs < 2; ++qs) {
        const float inv = 1.f / lacc[qs][0];
        u16* Cb = Ctx + (size_t)(b * SS + q0 + qs * 16 + l16) * D + h * 64 + q4 * 4;
#pragma unroll
        for (int dt = 0; dt < 4; ++dt) {
            s16x4 w;
#pragma unroll
            for (int r = 0; r < 4; ++r) w[r] = (short)f2bf(ot[qs][dt][r] * inv);
            *(s16x4*)(Cb + dt * 16) = w;  // O[q][dv], dv = dt*16 + q4*4 + r
        }
    }
}

extern "C" void kernel_launch(void* const* d_in, const int* in_sizes, int n_in,
                              void* d_out, int out_size, void* d_ws, size_t ws_size,
                              hipStream_t stream) {
    const float* query = (const float*)d_in[0];
    const float* key   = (const float*)d_in[1];
    const float* value = (const float*)d_in[2];
    const float* w_q   = (const float*)d_in[3];
    const float* w_k   = (const float*)d_in[4];
    const float* w_v   = (const float*)d_in[5];
    const float* w_o   = (const float*)d_in[6];
    float* out = (float*)d_out;

    const size_t MEG = 1024 * 1024;
    if (ws_size < 64 * MEG) return;  // layout needs 64 MiB
    u16* ws = (u16*)d_ws;
    u16* qb    = ws;
    u16* kb    = ws + 4 * MEG;
    u16* vb    = ws + 8 * MEG;
    u16* wqb   = ws + 12 * MEG;
    u16* wkb   = ws + 13 * MEG;
    u16* wvb   = ws + 14 * MEG;
    u16* wob   = ws + 15 * MEG;  // live until gemm_out
    u16* Qp    = ws + 16 * MEG;
    u16* Kp    = ws + 20 * MEG;
    u16* VtAll = ws + 24 * MEG;
    u16* ctx   = ws + 28 * MEG;  // ends at 32 MEG u16 = 64 MiB

    cvt_all<<<dim3(4096, 7), 256, 0, stream>>>(query, key, value, w_q, w_k, w_v, w_o,
                                               qb, kb, vb, wqb, wkb, wvb, wob);
    gemm_qkv<<<dim3(256, 3), 256, 0, stream>>>(qb, kb, vb, wqb, wkb, wvb, Qp, Kp, VtAll);
    flash_attn<<<dim3(16, 16, 2), 256, 0, stream>>>(Qp, Kp, VtAll, ctx);
    gemm_out<<<dim3(512), 256, 0, stream>>>(ctx, wob, out);
}

// Round 8
// 217.597 us; speedup vs baseline: 1.3102x; 1.3102x over previous
//
#include <hip/hip_runtime.h>

typedef unsigned short u16;
typedef unsigned int u32;
typedef __bf16 bf16x8 __attribute__((ext_vector_type(8)));
typedef float f32x4 __attribute__((ext_vector_type(4)));
typedef short s16x4 __attribute__((ext_vector_type(4)));

#define AS1 __attribute__((address_space(1)))
#define AS3 __attribute__((address_space(3)))

__device__ __forceinline__ f32x4 mfma16(bf16x8 a, bf16x8 b, f32x4 c) {
    return __builtin_amdgcn_mfma_f32_16x16x32_bf16(a, b, c, 0, 0, 0);
}
// K=16 shape: B-operand layout == C/D layout (transpose-free PV)
__device__ __forceinline__ f32x4 mfma16k16(s16x4 a, s16x4 b, f32x4 c) {
    return __builtin_amdgcn_mfma_f32_16x16x16bf16_1k(a, b, c, 0, 0, 0);
}

__device__ __forceinline__ u16 f2bf(float f) {
    return __builtin_bit_cast(u16, (__bf16)f);
}

__device__ __forceinline__ void gld16(const u16* g, u16* l) {
    __builtin_amdgcn_global_load_lds((AS1 void*)g, (AS3 void*)l, 16, 0, 0);
}

// ---------------- fused fp32 -> bf16 conversion ----------------
__global__ __launch_bounds__(256) void cvt_all(const float* __restrict__ q, const float* __restrict__ k,
                                               const float* __restrict__ v, const float* __restrict__ wq,
                                               const float* __restrict__ wk, const float* __restrict__ wv,
                                               const float* __restrict__ wo, u16* __restrict__ qo,
                                               u16* __restrict__ ko, u16* __restrict__ vo,
                                               u16* __restrict__ wqo, u16* __restrict__ wko,
                                               u16* __restrict__ wvo, u16* __restrict__ woo) {
    const int y = blockIdx.y;
    const float* x; u16* o; int n;
    switch (y) {
        case 0: x = q; o = qo; n = 4 << 20; break;
        case 1: x = k; o = ko; n = 4 << 20; break;
        case 2: x = v; o = vo; n = 4 << 20; break;
        case 3: x = wq; o = wqo; n = 1 << 20; break;
        case 4: x = wk; o = wko; n = 1 << 20; break;
        case 5: x = wv; o = wvo; n = 1 << 20; break;
        default: x = wo; o = woo; n = 1 << 20; break;
    }
    int i = (blockIdx.x * 256 + threadIdx.x) * 4;
    if (i >= n) return;
    float4 vv = *(const float4*)(x + i);
    u32 lo = (u32)f2bf(vv.x) | ((u32)f2bf(vv.y) << 16);
    u32 hi = (u32)f2bf(vv.z) | ((u32)f2bf(vv.w) << 16);
    *(uint2*)(o + i) = make_uint2(lo, hi);
}

// ---------------- GEMM: C[.,N] = A[.,K] @ Bt[N,K]^T, BK=64 ----------------
// Staging: row r of a tile occupies 64 u16 (128 B); 16B chunk c of row r stored at
// position c^(r&7) (global-source XOR, gld16 dest = wave-uniform + lane*16B).
// Fragment b128 reads: per 16-lane phase, 8 distinct bank-quads, 2-way (free).
// Two barriers per BK=64 step -> half the barrier count of BK=32.
template <int BM, int BN, bool BF16OUT>
__device__ __forceinline__ void gemm_core(const u16* __restrict__ A, const u16* __restrict__ Bt,
                                          void* __restrict__ Cp, int K, int N, int m0, int n0,
                                          float oscale) {
    constexpr int WROWS = BM / 64;        // 2 (128x128) or 1 (64x128)
    constexpr int WCOLS = 4 / WROWS;      // 2 or 4
    constexpr int BFR = BN / WCOLS / 16;  // 4 or 2
    __shared__ __align__(16) u16 As[BM * 64];
    __shared__ __align__(16) u16 Bs[BN * 64];
    const int tid = threadIdx.x;
    const int lane = tid & 63, wave = tid >> 6;
    const int l16 = lane & 15, q4 = lane >> 4;
    const int wm = (wave / WCOLS) * 64, wn = (wave % WCOLS) * (BFR * 16);

    const f32x4 fz = {0.f, 0.f, 0.f, 0.f};
    f32x4 acc[4][BFR];
#pragma unroll
    for (int i = 0; i < 4; ++i)
#pragma unroll
        for (int j = 0; j < BFR; ++j) acc[i][j] = fz;

    // staging unit u = 8 rows (u*8..u*8+7): one wave-gld16 (lane covers row u*8+(lane>>3),
    // source 16B chunk (lane&7)^(row&7), dest = As + u*512 + lane*8 elems)
    const int ck = ((lane & 7) ^ (lane >> 3)) * 8;
    const u16* Ag = A + (size_t)(m0 + (lane >> 3)) * K + ck;
    const u16* Bg = Bt + (size_t)(n0 + (lane >> 3)) * K + ck;

    const int posb = (q4 ^ (l16 & 7)) * 8;  // frag chunk position, k-low half; high = ^32

    for (int k0 = 0; k0 < K; k0 += 64) {
        __syncthreads();
#pragma unroll
        for (int uu = 0; uu < BM / 32; ++uu) {
            const int u = wave + uu * 4;
            gld16(Ag + (size_t)u * 8 * K + k0, As + u * 512);
        }
#pragma unroll
        for (int uu = 0; uu < BN / 32; ++uu) {
            const int u = wave + uu * 4;
            gld16(Bg + (size_t)u * 8 * K + k0, Bs + u * 512);
        }
        __syncthreads();
#pragma unroll
        for (int s = 0; s < 2; ++s) {  // k-sub-halves of the 64-wide stage
            const int sx = s * 32;
            bf16x8 af[4], bfr[BFR];
#pragma unroll
            for (int i = 0; i < 4; ++i)
                af[i] = *(const bf16x8*)&As[(wm + i * 16 + l16) * 64 + (posb ^ sx)];
#pragma unroll
            for (int j = 0; j < BFR; ++j)
                bfr[j] = *(const bf16x8*)&Bs[(wn + j * 16 + l16) * 64 + (posb ^ sx)];
#pragma unroll
            for (int i = 0; i < 4; ++i)
#pragma unroll
                for (int j = 0; j < BFR; ++j) acc[i][j] = mfma16(af[i], bfr[j], acc[i][j]);
        }
    }

#pragma unroll
    for (int i = 0; i < 4; ++i) {
        const int row = m0 + wm + i * 16 + q4 * 4;
#pragma unroll
        for (int j = 0; j < BFR; ++j) {
            const int col = n0 + wn + j * 16 + l16;
#pragma unroll
            for (int r = 0; r < 4; ++r) {
                const float vr = acc[i][j][r] * oscale;
                if constexpr (BF16OUT)
                    ((u16*)Cp)[(size_t)(row + r) * N + col] = f2bf(vr);
                else
                    ((float*)Cp)[(size_t)(row + r) * N + col] = vr;
            }
        }
    }
}

// z=0: Q = query@wq^T (pre-scaled by 0.125*log2e); z=1: K = key@wk^T;
// z=2: Vt = wv @ value^T -> VtAll[h*64+dv][b*2048+s]
__global__ __launch_bounds__(256) void gemm_qkv(const u16* __restrict__ qb, const u16* __restrict__ kb,
                                                const u16* __restrict__ vb, const u16* __restrict__ wqb,
                                                const u16* __restrict__ wkb, const u16* __restrict__ wvb,
                                                u16* __restrict__ Qp, u16* __restrict__ Kp,
                                                u16* __restrict__ VtAll) {
    const int z = blockIdx.y, x = blockIdx.x;
    const u16 *A, *Bt;
    u16* C;
    int N, m0, n0;
    float sc = 1.0f;
    if (z == 0) {
        A = qb; Bt = wqb; C = Qp; N = 1024; m0 = (x >> 3) * 128; n0 = (x & 7) * 128;
        sc = 0.18033688011112042f;  // (1/sqrt(64)) * log2(e)
    } else if (z == 1) {
        A = kb; Bt = wkb; C = Kp; N = 1024; m0 = (x >> 3) * 128; n0 = (x & 7) * 128;
    } else {
        A = wvb; Bt = vb; C = VtAll; N = 4096; m0 = (x >> 5) * 128; n0 = (x & 31) * 128;
    }
    gemm_core<128, 128, true>(A, Bt, C, 1024, N, m0, n0, sc);
}

__global__ __launch_bounds__(256) void gemm_out(const u16* __restrict__ ctx,
                                                const u16* __restrict__ wob,
                                                float* __restrict__ out) {
    const int x = blockIdx.x;  // 512 blocks: 64 m-tiles x 8 n-tiles
    gemm_core<64, 128, false>(ctx, wob, out, 1024, 1024, (x >> 3) * 64, (x & 7) * 128, 1.0f);
}

// ---------------- Flash attention: K AND V async-dbuf in LDS via gld16 ------------------
// Loop t: barrier (vmcnt(0) drain = buf[t] ready, buf[t^1] readers done) -> issue 4 gld16
// for tile t+1 into buf[t^1] -> compute t. One barrier per tile; staging has a full tile
// of compute to land. Same XOR chunk-swizzle as gemm staging: chunk c of row r at c^(r&7).
// K b128 frag reads and V b64 frag reads are both 2-way bank aliasing (free).
__global__ __launch_bounds__(256) void flash_attn(const u16* __restrict__ Qp,
                                                  const u16* __restrict__ Kp,
                                                  const u16* __restrict__ VtAll,
                                                  u16* __restrict__ Ctx) {
    constexpr int D = 1024, SS = 2048;
    __shared__ __align__(16) u16 Ks[2][64 * 64];  // [buf][s_row][dk], chunk-swizzled
    __shared__ __align__(16) u16 Vs[2][64 * 64];  // [buf][dv_row][s], chunk-swizzled

    const int tid = threadIdx.x;
    const int lane = tid & 63, wave = tid >> 6;
    const int l16 = lane & 15, q4 = lane >> 4;
    const int h = blockIdx.y, b = blockIdx.z;
    const int q0 = blockIdx.x * 128 + wave * 32;

    bf16x8 qf[2][2];
#pragma unroll
    for (int qs = 0; qs < 2; ++qs) {
        const u16* Qb = Qp + (size_t)(b * SS + q0 + qs * 16 + l16) * D + h * 64;
        qf[qs][0] = *(const bf16x8*)(Qb + q4 * 8);
        qf[qs][1] = *(const bf16x8*)(Qb + 32 + q4 * 8);
    }

    const f32x4 fz = {0.f, 0.f, 0.f, 0.f};
    f32x4 ot[2][4], lacc[2];
    lacc[0] = fz; lacc[1] = fz;
#pragma unroll
    for (int qs = 0; qs < 2; ++qs)
#pragma unroll
        for (int dt = 0; dt < 4; ++dt) ot[qs][dt] = fz;

    s16x4 onesA;
    onesA[0] = onesA[1] = onesA[2] = onesA[3] = (short)0x3F80;  // bf16 1.0

    // staging: thread covers rows sr and sr+32 (sr = tid>>3); source chunk XOR'd by row&7
    const int sr = tid >> 3;
    const int ck = ((lane & 7) ^ (lane >> 3)) * 8;
    const u16* Kg = Kp + (size_t)(b * SS + sr) * D + h * 64 + ck;
    const u16* Vg = VtAll + (size_t)(h * 64 + sr) * 4096 + (size_t)b * SS + ck;
    const int ldsW = wave * 512;  // u16 elems; wave-uniform gld16 dest base

    // preload tile 0 into buf 0
    gld16(Kg, &Ks[0][ldsW]);
    gld16(Kg + (size_t)32 * D, &Ks[0][ldsW + 2048]);
    gld16(Vg, &Vs[0][ldsW]);
    gld16(Vg + (size_t)32 * 4096, &Vs[0][ldsW + 2048]);

    const int posK = (q4 ^ (l16 & 7)) * 8;  // K-frag chunk pos (dk-low); dk-high = ^32
    const int x7 = l16 & 7, q4h = q4 >> 1, q4l = (q4 & 1) * 4;  // V-frag index parts

    for (int kt = 0; kt < SS; kt += 64) {
        const int buf = (kt >> 6) & 1;
        __syncthreads();  // vmcnt(0)+barrier: buf ready; buf^1 free to overwrite
        if (kt + 64 < SS) {  // async prefetch next tile; lands by next barrier
            gld16(Kg + (size_t)(kt + 64) * D, &Ks[buf ^ 1][ldsW]);
            gld16(Kg + (size_t)(kt + 96) * D, &Ks[buf ^ 1][ldsW + 2048]);
            gld16(Vg + kt + 64, &Vs[buf ^ 1][ldsW]);
            gld16(Vg + (size_t)32 * 4096 + kt + 64, &Vs[buf ^ 1][ldsW + 2048]);
        }

        // S^T = K·Q^T (exp2 domain; Q pre-scaled by 0.125*log2e)
        f32x4 st[2][4];
#pragma unroll
        for (int nt = 0; nt < 4; ++nt) {
            const int R = (nt * 16 + l16) * 64;
            const bf16x8 ka = *(const bf16x8*)&Ks[buf][R + posK];
            const bf16x8 kbf = *(const bf16x8*)&Ks[buf][R + (posK ^ 32)];
#pragma unroll
            for (int qs = 0; qs < 2; ++qs) {
                f32x4 s = mfma16(ka, qf[qs][0], fz);
                st[qs][nt] = mfma16(kbf, qf[qs][1], s);
            }
        }
        // P^T = exp2(S^T), in-register (K=16 B-frag layout)
        s16x4 p[2][4];
#pragma unroll
        for (int qs = 0; qs < 2; ++qs)
#pragma unroll
            for (int nt = 0; nt < 4; ++nt) {
                s16x4 pk;
#pragma unroll
                for (int r = 0; r < 4; ++r)
                    pk[r] = (short)f2bf(__builtin_amdgcn_exp2f(st[qs][nt][r]));
                p[qs][nt] = pk;
            }
        // O^T += V^T·P^T ; l via ones-MFMA (every reg = l[q=l16])
        // V A-frag: logical row dt*16+l16, col nt*16+q4*4+j -> swizzled chunk pos
        // (nt*2+(q4>>1))^(l16&7), sub-offset (q4&1)*4
#pragma unroll
        for (int nt = 0; nt < 4; ++nt) {
#pragma unroll
            for (int dt = 0; dt < 4; ++dt) {
                const s16x4 va = *(const s16x4*)
                    &Vs[buf][(dt * 16 + l16) * 64 + (((nt * 2 + q4h) ^ x7) * 8 + q4l)];
                ot[0][dt] = mfma16k16(va, p[0][nt], ot[0][dt]);
                ot[1][dt] = mfma16k16(va, p[1][nt], ot[1][dt]);
            }
            lacc[0] = mfma16k16(onesA, p[0][nt], lacc[0]);
            lacc[1] = mfma16k16(onesA, p[1][nt], lacc[1]);
        }
    }

    // normalize + direct bf16 ctx write (lacc broadcast: all regs hold l[q=l16])
#pragma unroll
    for (int qs = 0; qs < 2; ++qs) {
        const float inv = 1.f / lacc[qs][0];
        u16* Cb = Ctx + (size_t)(b * SS + q0 + qs * 16 + l16) * D + h * 64 + q4 * 4;
#pragma unroll
        for (int dt = 0; dt < 4; ++dt) {
            s16x4 w;
#pragma unroll
            for (int r = 0; r < 4; ++r) w[r] = (short)f2bf(ot[qs][dt][r] * inv);
            *(s16x4*)(Cb + dt * 16) = w;  // O[q][dv], dv = dt*16 + q4*4 + r
        }
    }
}

extern "C" void kernel_launch(void* const* d_in, const int* in_sizes, int n_in,
                              void* d_out, int out_size, void* d_ws, size_t ws_size,
                              hipStream_t stream) {
    const float* query = (const float*)d_in[0];
    const float* key   = (const float*)d_in[1];
    const float* value = (const float*)d_in[2];
    const float* w_q   = (const float*)d_in[3];
    const float* w_k   = (const float*)d_in[4];
    const float* w_v   = (const float*)d_in[5];
    const float* w_o   = (const float*)d_in[6];
    float* out = (float*)d_out;

    const size_t MEG = 1024 * 1024;
    if (ws_size < 64 * MEG) return;  // layout needs 64 MiB
    u16* ws = (u16*)d_ws;
    u16* qb    = ws;
    u16* kb    = ws + 4 * MEG;
    u16* vb    = ws + 8 * MEG;
    u16* wqb   = ws + 12 * MEG;
    u16* wkb   = ws + 13 * MEG;
    u16* wvb   = ws + 14 * MEG;
    u16* wob   = ws + 15 * MEG;  // live until gemm_out
    u16* Qp    = ws + 16 * MEG;
    u16* Kp    = ws + 20 * MEG;
    u16* VtAll = ws + 24 * MEG;
    u16* ctx   = ws + 28 * MEG;  // ends at 32 MEG u16 = 64 MiB

    cvt_all<<<dim3(4096, 7), 256, 0, stream>>>(query, key, value, w_q, w_k, w_v, w_o,
                                               qb, kb, vb, wqb, wkb, wvb, wob);
    gemm_qkv<<<dim3(256, 3), 256, 0, stream>>>(qb, kb, vb, wqb, wkb, wvb, Qp, Kp, VtAll);
    flash_attn<<<dim3(16, 16, 2), 256, 0, stream>>>(Qp, Kp, VtAll, ctx);
    gemm_out<<<dim3(512), 256, 0, stream>>>(ctx, wob, out);
}